// Round 7
// baseline (168.778 us; speedup 1.0000x reference)
//
#include <hip/hip_runtime.h>

#define DIM 32
#define NPB 128            // nodes per bucket (shift 7); sort_aggregate assumes 128
#define NPB_SHIFT 7
#define NPB_MASK 127
#define MAXB 1024          // max buckets supported by LDS hists / scan
#define PCHUNK 4096        // edges per hist/partition block (512 thr x 8 edges)
#define GPAD 16            // ghist/gcur padding: one counter per 64B line
#define CAP 4096           // edges sorted per pass in LDS
#define TILE 8192          // legacy scan tile (fallback path)

// ================= bucketed sort-aggregate path =================

__global__ void zero_i32_kernel(int* __restrict__ p, int n) {
    int t = blockIdx.x * blockDim.x + threadIdx.x;
    if (t < n) p[t] = 0;
}

// Block-local histogram of bucket ids, flushed with one global atomic per
// (block, bucket) into a 64B-padded counter array (no false sharing).
__global__ void __launch_bounds__(512)
bucket_hist_kernel(const int* __restrict__ dst, int* __restrict__ ghist,
                   int n_edges, int nbuckets) {
    __shared__ int lh[MAXB];
    for (int j = threadIdx.x; j < nbuckets; j += 512) lh[j] = 0;
    __syncthreads();
    int c0 = blockIdx.x * PCHUNK;
    int c1 = min(c0 + PCHUNK, n_edges);
    for (int base = c0 + threadIdx.x * 4; base < c1; base += 512 * 4) {
        if (base + 3 < c1) {
            int4 d = *(const int4*)(dst + base);
            atomicAdd(&lh[d.x >> NPB_SHIFT], 1);
            atomicAdd(&lh[d.y >> NPB_SHIFT], 1);
            atomicAdd(&lh[d.z >> NPB_SHIFT], 1);
            atomicAdd(&lh[d.w >> NPB_SHIFT], 1);
        } else {
            for (int k = base; k < c1; ++k)
                atomicAdd(&lh[dst[k] >> NPB_SHIFT], 1);
        }
    }
    __syncthreads();
    for (int j = threadIdx.x; j < nbuckets; j += 512)
        if (lh[j]) atomicAdd(&ghist[j * GPAD], lh[j]);
}

// Single-block exclusive scan of <=MAXB padded bucket counts
// -> goff (compact, preserved) + gcur (padded cursors).
__global__ void bucket_scan_kernel(const int* __restrict__ ghist,
                                   int* __restrict__ goff,
                                   int* __restrict__ gcur, int nbuckets) {
    __shared__ int sh[MAXB];
    int t = threadIdx.x;
    int v = (t < nbuckets) ? ghist[t * GPAD] : 0;
    sh[t] = v;
    __syncthreads();
    for (int off = 1; off < MAXB; off <<= 1) {
        int u = (t >= off) ? sh[t - off] : 0;
        __syncthreads();
        sh[t] += u;
        __syncthreads();
    }
    if (t < nbuckets) {
        int excl = sh[t] - v;
        goff[t] = excl;
        gcur[t * GPAD] = excl;
    }
}

// Partition edges into bucket-contiguous packed array.
// packed = (src << NPB_SHIFT) | (dst & NPB_MASK)
// dst values are register-cached across the barrier (read once, int4).
__global__ void __launch_bounds__(512)
partition_kernel(const int* __restrict__ src, const int* __restrict__ dst,
                 int* __restrict__ gcur, int* __restrict__ packed,
                 int n_edges, int nbuckets) {
    __shared__ int lh[MAXB];
    __shared__ int lbase[MAXB];
    __shared__ int lrank[MAXB];
    for (int j = threadIdx.x; j < nbuckets; j += 512) {
        lh[j] = 0;
        lrank[j] = 0;
    }
    __syncthreads();
    int c0 = blockIdx.x * PCHUNK;
    int c1 = min(c0 + PCHUNK, n_edges);
    int i0 = c0 + threadIdx.x * 4;
    int i1 = i0 + 2048;                 // second int4 group

    int4 da = {0, 0, 0, 0}, db = {0, 0, 0, 0};
    int na = 0, nb2 = 0;
    if (i0 + 3 < c1) { da = *(const int4*)(dst + i0); na = 4; }
    else if (i0 < c1) { na = c1 - i0; int* dp = (int*)&da;
                        for (int k = 0; k < na; ++k) dp[k] = dst[i0 + k]; }
    if (i1 + 3 < c1) { db = *(const int4*)(dst + i1); nb2 = 4; }
    else if (i1 < c1) { nb2 = c1 - i1; int* dp = (int*)&db;
                        for (int k = 0; k < nb2; ++k) dp[k] = dst[i1 + k]; }

    // pass 1: local hist from cached dst
    {
        int* dp = (int*)&da;
        for (int k = 0; k < na; ++k) atomicAdd(&lh[dp[k] >> NPB_SHIFT], 1);
        dp = (int*)&db;
        for (int k = 0; k < nb2; ++k) atomicAdd(&lh[dp[k] >> NPB_SHIFT], 1);
    }
    __syncthreads();
    // reserve contiguous global ranges per bucket (padded cursors)
    for (int j = threadIdx.x; j < nbuckets; j += 512)
        lbase[j] = lh[j] ? atomicAdd(&gcur[j * GPAD], lh[j]) : 0;
    __syncthreads();
    // pass 2: read src (int4), scatter packed into reserved ranges
    int4 sa = {0, 0, 0, 0}, sb = {0, 0, 0, 0};
    if (na == 4) sa = *(const int4*)(src + i0);
    else { int* sp = (int*)&sa; for (int k = 0; k < na; ++k) sp[k] = src[i0 + k]; }
    if (nb2 == 4) sb = *(const int4*)(src + i1);
    else { int* sp = (int*)&sb; for (int k = 0; k < nb2; ++k) sp[k] = src[i1 + k]; }

    {
        int* dp = (int*)&da; int* sp = (int*)&sa;
        for (int k = 0; k < na; ++k) {
            int d = dp[k], b = d >> NPB_SHIFT;
            int r = atomicAdd(&lrank[b], 1);
            packed[lbase[b] + r] = (sp[k] << NPB_SHIFT) | (d & NPB_MASK);
        }
        dp = (int*)&db; sp = (int*)&sb;
        for (int k = 0; k < nb2; ++k) {
            int d = dp[k], b = d >> NPB_SHIFT;
            int r = atomicAdd(&lrank[b], 1);
            packed[lbase[b] + r] = (sp[k] << NPB_SHIFT) | (d & NPB_MASK);
        }
    }
}

__device__ inline void f4add(float4& a, float4 v) {
    a.x += v.x; a.y += v.y; a.z += v.z; a.w += v.w;
}

// Sum x4 rows listed in LDS `sorted[s0 .. s0+cnt)` into two partial float4 accs.
__device__ inline void accum_node(const float4* __restrict__ x4,
                                  const int* sorted, int s0, int cnt, int q,
                                  float4& accA, float4& accB) {
    int k = 0;
    for (; k + 3 < cnt; k += 4) {
        int i0 = sorted[s0 + k];
        int i1 = sorted[s0 + k + 1];
        int i2 = sorted[s0 + k + 2];
        int i3 = sorted[s0 + k + 3];
        float4 v0 = x4[i0 * 8 + q];
        float4 v1 = x4[i1 * 8 + q];
        float4 v2 = x4[i2 * 8 + q];
        float4 v3 = x4[i3 * 8 + q];
        f4add(accA, v0); f4add(accB, v1); f4add(accA, v2); f4add(accB, v3);
    }
    for (; k < cnt; ++k) f4add(accA, x4[sorted[s0 + k] * 8 + q]);
}

// One 512-thread block per 128-node bucket: in-LDS counting sort of the
// bucket's edges by local dst, then atomic-free register accumulation.
__global__ void __launch_bounds__(512)
sort_aggregate_kernel(const float4* __restrict__ x4,
                      const int* __restrict__ goff,
                      const int* __restrict__ packed,
                      float4* __restrict__ out4,
                      int n_nodes, int n_edges, int nbuckets) {
    __shared__ int shist[NPB];
    __shared__ int soff[NPB];
    __shared__ int scur[NPB];
    __shared__ int sorted[CAP];

    int b = blockIdx.x;
    int n0 = b << NPB_SHIFT;
    int t = threadIdx.x;
    int seg_start = goff[b];
    int seg_end   = (b + 1 < nbuckets) ? goff[b + 1] : n_edges;

    int node = t >> 3;        // 0..63 (batch 0: node, batch 1: node+64)
    int q    = t & 7;         // feature quad
    float4 a0A = {0,0,0,0}, a0B = {0,0,0,0};
    float4 a1A = {0,0,0,0}, a1B = {0,0,0,0};
    int deg0 = 0, deg1 = 0;

    for (int pos = seg_start; pos < seg_end; pos += CAP) {
        int chunk = min(CAP, seg_end - pos);
        for (int i = t; i < NPB; i += 512) shist[i] = 0;
        __syncthreads();
        for (int i = t; i < chunk; i += 512)
            atomicAdd(&shist[packed[pos + i] & NPB_MASK], 1);
        __syncthreads();
        if (t < NPB) soff[t] = shist[t];
        __syncthreads();
        for (int off = 1; off < NPB; off <<= 1) {
            int v = (t < NPB && t >= off) ? soff[t - off] : 0;
            __syncthreads();
            if (t < NPB) soff[t] += v;
            __syncthreads();
        }
        if (t < NPB) {
            int e = soff[t] - shist[t];
            soff[t] = e;
            scur[t] = e;
        }
        __syncthreads();
        for (int i = t; i < chunk; i += 512) {
            int p = packed[pos + i];
            int r = atomicAdd(&scur[p & NPB_MASK], 1);
            sorted[r] = p >> NPB_SHIFT;
        }
        __syncthreads();
        {
            int c0 = shist[node];
            accum_node(x4, sorted, soff[node], c0, q, a0A, a0B);
            deg0 += c0;
            int c1 = shist[node + 64];
            accum_node(x4, sorted, soff[node + 64], c1, q, a1A, a1B);
            deg1 += c1;
        }
        __syncthreads();
    }

    int g0 = n0 + node;
    if (g0 < n_nodes) {
        float inv = 1.0f / (float)max(deg0, 1);
        float4 r;
        r.x = (a0A.x + a0B.x) * inv; r.y = (a0A.y + a0B.y) * inv;
        r.z = (a0A.z + a0B.z) * inv; r.w = (a0A.w + a0B.w) * inv;
        out4[g0 * 8 + q] = r;
    }
    int g1 = n0 + 64 + node;
    if (g1 < n_nodes) {
        float inv = 1.0f / (float)max(deg1, 1);
        float4 r;
        r.x = (a1A.x + a1B.x) * inv; r.y = (a1A.y + a1B.y) * inv;
        r.z = (a1A.z + a1B.z) * inv; r.w = (a1A.w + a1B.w) * inv;
        out4[g1 * 8 + q] = r;
    }
}

// ================= fallback: sorted (pull) path =================

__global__ void hist_kernel(const int* __restrict__ dst, int* __restrict__ counts,
                            int n_edges) {
    int t = blockIdx.x * blockDim.x + threadIdx.x;
    if (t < n_edges) atomicAdd(&counts[dst[t]], 1);
}

__global__ void scan_part1(const int* __restrict__ counts,
                           int* __restrict__ block_sums, int n) {
    __shared__ int sh[256];
    int base = blockIdx.x * TILE + threadIdx.x * 32;
    int s = 0;
#pragma unroll
    for (int i = 0; i < 32; ++i) {
        int idx = base + i;
        if (idx < n) s += counts[idx];
    }
    sh[threadIdx.x] = s;
    __syncthreads();
    for (int off = 128; off > 0; off >>= 1) {
        if (threadIdx.x < off) sh[threadIdx.x] += sh[threadIdx.x + off];
        __syncthreads();
    }
    if (threadIdx.x == 0) block_sums[blockIdx.x] = sh[0];
}

__global__ void scan_part2(int* __restrict__ block_sums, int nb) {
    if (blockIdx.x == 0 && threadIdx.x == 0) {
        int run = 0;
        for (int i = 0; i < nb; ++i) {
            int v = block_sums[i];
            block_sums[i] = run;
            run += v;
        }
    }
}

__global__ void scan_part3(const int* __restrict__ counts,
                           const int* __restrict__ block_sums,
                           int* __restrict__ offsets, int n) {
    __shared__ int sh[256];
    int tid = threadIdx.x;
    int base = blockIdx.x * TILE + tid * 32;
    int local[32];
    int s = 0;
#pragma unroll
    for (int i = 0; i < 32; ++i) {
        int idx = base + i;
        int v = (idx < n) ? counts[idx] : 0;
        local[i] = v;
        s += v;
    }
    sh[tid] = s;
    __syncthreads();
    for (int off = 1; off < 256; off <<= 1) {
        int v = (tid >= off) ? sh[tid - off] : 0;
        __syncthreads();
        sh[tid] += v;
        __syncthreads();
    }
    int run = block_sums[blockIdx.x] + ((tid == 0) ? 0 : sh[tid - 1]);
#pragma unroll
    for (int i = 0; i < 32; ++i) {
        int idx = base + i;
        if (idx < n) offsets[idx] = run;
        run += local[i];
    }
}

__global__ void scatter_sort_kernel(const int* __restrict__ src,
                                    const int* __restrict__ dst,
                                    int* __restrict__ cursors,
                                    int* __restrict__ sorted_src,
                                    int n_edges) {
    int t = blockIdx.x * blockDim.x + threadIdx.x;
    if (t < n_edges) {
        int pos = atomicAdd(&cursors[dst[t]], 1);
        sorted_src[pos] = src[t];
    }
}

__global__ void aggregate_kernel(const float* __restrict__ x,
                                 const int* __restrict__ seg_end,
                                 const int* __restrict__ sorted_src,
                                 float4* __restrict__ out,
                                 int n_nodes) {
    int t = blockIdx.x * blockDim.x + threadIdx.x;
    int n = t >> 3;
    if (n >= n_nodes) return;
    int q = t & 7;
    int end   = seg_end[n];
    int start = (n == 0) ? 0 : seg_end[n - 1];
    const float4* x4 = (const float4*)x;
    float4 acc0 = make_float4(0.f, 0.f, 0.f, 0.f);
    float4 acc1 = make_float4(0.f, 0.f, 0.f, 0.f);
    int k = start;
    for (; k + 1 < end; k += 2) {
        int s0 = sorted_src[k];
        int s1 = sorted_src[k + 1];
        f4add(acc0, x4[s0 * 8 + q]);
        f4add(acc1, x4[s1 * 8 + q]);
    }
    if (k < end) f4add(acc0, x4[sorted_src[k] * 8 + q]);
    float inv = 1.0f / (float)max(end - start, 1);
    float4 r;
    r.x = (acc0.x + acc1.x) * inv;
    r.y = (acc0.y + acc1.y) * inv;
    r.z = (acc0.z + acc1.z) * inv;
    r.w = (acc0.w + acc1.w) * inv;
    out[n * 8 + q] = r;
}

// ================= launch =================

extern "C" void kernel_launch(void* const* d_in, const int* in_sizes, int n_in,
                              void* d_out, int out_size, void* d_ws, size_t ws_size,
                              hipStream_t stream) {
    const float* x   = (const float*)d_in[0];
    const int*   src = (const int*)d_in[1];
    const int*   dst = (const int*)d_in[2];
    float* out = (float*)d_out;

    int n_nodes = in_sizes[0] / DIM;
    int n_edges = in_sizes[1];
    int n_out   = out_size;

    int nbuckets = (n_nodes + NPB - 1) >> NPB_SHIFT;
    size_t need_new = ((size_t)2 * nbuckets * GPAD + nbuckets + n_edges) * sizeof(int);
    bool pack_ok = (n_nodes < (1 << 24)) && (nbuckets <= MAXB);

    if (pack_ok && ws_size >= need_new) {
        int* ghist  = (int*)d_ws;                    // [nbuckets*GPAD] padded
        int* gcur   = ghist + (size_t)nbuckets * GPAD; // [nbuckets*GPAD] padded
        int* goff   = gcur + (size_t)nbuckets * GPAD;  // [nbuckets] compact
        int* packed = goff + nbuckets;               // [n_edges]

        int zn = nbuckets * GPAD;
        zero_i32_kernel<<<(zn + 255) / 256, 256, 0, stream>>>(ghist, zn);

        int pblocks = (n_edges + PCHUNK - 1) / PCHUNK;
        bucket_hist_kernel<<<pblocks, 512, 0, stream>>>(dst, ghist, n_edges,
                                                        nbuckets);
        bucket_scan_kernel<<<1, MAXB, 0, stream>>>(ghist, goff, gcur, nbuckets);
        partition_kernel<<<pblocks, 512, 0, stream>>>(src, dst, gcur, packed,
                                                      n_edges, nbuckets);
        sort_aggregate_kernel<<<nbuckets, 512, 0, stream>>>((const float4*)x, goff,
                                                            packed, (float4*)out,
                                                            n_nodes, n_edges,
                                                            nbuckets);
    } else {
        // fallback: dst-sorted pull path (round-4 pipeline)
        int nb = (n_nodes + TILE - 1) / TILE;
        int* counts     = (int*)d_ws;
        int* offsets    = counts + n_nodes;
        int* sorted_src = offsets + n_nodes;
        int* block_sums = sorted_src + n_edges;

        zero_i32_kernel<<<(n_nodes + 255) / 256, 256, 0, stream>>>(counts, n_nodes);
        int eb = (n_edges + 255) / 256;
        hist_kernel<<<eb, 256, 0, stream>>>(dst, counts, n_edges);
        scan_part1<<<nb, 256, 0, stream>>>(counts, block_sums, n_nodes);
        scan_part2<<<1, 64, 0, stream>>>(block_sums, nb);
        scan_part3<<<nb, 256, 0, stream>>>(counts, block_sums, offsets, n_nodes);
        scatter_sort_kernel<<<eb, 256, 0, stream>>>(src, dst, offsets, sorted_src,
                                                    n_edges);
        int athreads = n_nodes * 8;
        int ab = (athreads + 255) / 256;
        aggregate_kernel<<<ab, 256, 0, stream>>>(x, offsets, sorted_src,
                                                 (float4*)out, n_nodes);
    }
}

// Round 8
// 130.175 us; speedup vs baseline: 1.2965x; 1.2965x over previous
//
#include <hip/hip_runtime.h>

#define DIM 32
#define NPB 128            // nodes per bucket (shift 7); sort_aggregate assumes 128
#define NPB_SHIFT 7
#define NPB_MASK 127
#define MAXB 1024          // max buckets supported by LDS hists / scan
#define PCHUNK 8192        // edges per hist/partition block (512 thr x 16 edges)
#define MAXBLK 256         // max partition blocks (colscan loads one column/block)
#define CAP 4096           // edges sorted per pass in LDS
#define TILE 8192          // legacy scan tile (fallback path)

// ================= bucketed sort-aggregate path (atomic-free partition) ======

__global__ void zero_i32_kernel(int* __restrict__ p, int n) {
    int t = blockIdx.x * blockDim.x + threadIdx.x;
    if (t < n) p[t] = 0;
}

// Per-chunk LDS histogram of bucket ids -> non-atomic coalesced row write
// into H[b][nbuckets]. No global atomics.
__global__ void __launch_bounds__(512)
hist_kernel_na(const int* __restrict__ dst, int* __restrict__ H,
               int n_edges, int nbuckets) {
    __shared__ int lh[MAXB];
    for (int j = threadIdx.x; j < nbuckets; j += 512) lh[j] = 0;
    __syncthreads();
    int c0 = blockIdx.x * PCHUNK;
    int c1 = min(c0 + PCHUNK, n_edges);
#pragma unroll
    for (int g = 0; g < 4; ++g) {
        int i = c0 + g * 2048 + threadIdx.x * 4;
        if (i + 3 < c1) {
            int4 d = *(const int4*)(dst + i);
            atomicAdd(&lh[d.x >> NPB_SHIFT], 1);
            atomicAdd(&lh[d.y >> NPB_SHIFT], 1);
            atomicAdd(&lh[d.z >> NPB_SHIFT], 1);
            atomicAdd(&lh[d.w >> NPB_SHIFT], 1);
        } else {
            for (int k = i; k < c1; ++k)
                atomicAdd(&lh[dst[k] >> NPB_SHIFT], 1);
        }
    }
    __syncthreads();
    int* row = H + (size_t)blockIdx.x * nbuckets;
    for (int j = threadIdx.x; j < nbuckets; j += 512) row[j] = lh[j];
}

// One block per bucket: exclusive scan down the bucket's column of H
// (in place), column total -> colsum[j]. nblocks <= MAXBLK.
__global__ void __launch_bounds__(MAXBLK)
colscan_kernel(int* __restrict__ H, int* __restrict__ colsum,
               int nblocks, int nbuckets) {
    __shared__ int sh[MAXBLK];
    int j = blockIdx.x;
    int t = threadIdx.x;
    int v = (t < nblocks) ? H[(size_t)t * nbuckets + j] : 0;
    sh[t] = v;
    __syncthreads();
    for (int off = 1; off < MAXBLK; off <<= 1) {
        int u = (t >= off) ? sh[t - off] : 0;
        __syncthreads();
        sh[t] += u;
        __syncthreads();
    }
    if (t < nblocks) H[(size_t)t * nbuckets + j] = sh[t] - v;  // exclusive
    if (t == nblocks - 1) colsum[j] = sh[t];                   // total
}

// Single-block exclusive scan of <=MAXB values: colsum -> goff.
__global__ void __launch_bounds__(MAXB)
exscan_kernel(const int* __restrict__ in, int* __restrict__ out, int n) {
    __shared__ int sh[MAXB];
    int t = threadIdx.x;
    int v = (t < n) ? in[t] : 0;
    sh[t] = v;
    __syncthreads();
    for (int off = 1; off < MAXB; off <<= 1) {
        int u = (t >= off) ? sh[t - off] : 0;
        __syncthreads();
        sh[t] += u;
        __syncthreads();
    }
    if (t < n) out[t] = sh[t] - v;
}

// Partition edges into bucket-contiguous packed array.
// Block base per bucket = goff[j] + H[b][j] (coalesced row read; NO atomics).
// packed = (src << NPB_SHIFT) | (dst & NPB_MASK)
__global__ void __launch_bounds__(512)
partition_kernel_na(const int* __restrict__ src, const int* __restrict__ dst,
                    const int* __restrict__ H, const int* __restrict__ goff,
                    int* __restrict__ packed, int n_edges, int nbuckets) {
    __shared__ int lbase[MAXB];
    __shared__ int lrank[MAXB];
    const int* row = H + (size_t)blockIdx.x * nbuckets;
    for (int j = threadIdx.x; j < nbuckets; j += 512) {
        lbase[j] = goff[j] + row[j];
        lrank[j] = 0;
    }
    __syncthreads();
    int c0 = blockIdx.x * PCHUNK;
    int c1 = min(c0 + PCHUNK, n_edges);
#pragma unroll
    for (int g = 0; g < 4; ++g) {
        int i = c0 + g * 2048 + threadIdx.x * 4;
        if (i + 3 < c1) {
            int4 d = *(const int4*)(dst + i);
            int4 s = *(const int4*)(src + i);
            int b0 = d.x >> NPB_SHIFT;
            int b1 = d.y >> NPB_SHIFT;
            int b2 = d.z >> NPB_SHIFT;
            int b3 = d.w >> NPB_SHIFT;
            int r0 = atomicAdd(&lrank[b0], 1);
            int r1 = atomicAdd(&lrank[b1], 1);
            int r2 = atomicAdd(&lrank[b2], 1);
            int r3 = atomicAdd(&lrank[b3], 1);
            packed[lbase[b0] + r0] = (s.x << NPB_SHIFT) | (d.x & NPB_MASK);
            packed[lbase[b1] + r1] = (s.y << NPB_SHIFT) | (d.y & NPB_MASK);
            packed[lbase[b2] + r2] = (s.z << NPB_SHIFT) | (d.z & NPB_MASK);
            packed[lbase[b3] + r3] = (s.w << NPB_SHIFT) | (d.w & NPB_MASK);
        } else {
            for (int k = i; k < c1; ++k) {
                int d = dst[k];
                int b = d >> NPB_SHIFT;
                int r = atomicAdd(&lrank[b], 1);
                packed[lbase[b] + r] = (src[k] << NPB_SHIFT) | (d & NPB_MASK);
            }
        }
    }
}

__device__ inline void f4add(float4& a, float4 v) {
    a.x += v.x; a.y += v.y; a.z += v.z; a.w += v.w;
}

// Sum x4 rows listed in LDS `sorted[s0 .. s0+cnt)` into two partial float4 accs.
__device__ inline void accum_node(const float4* __restrict__ x4,
                                  const int* sorted, int s0, int cnt, int q,
                                  float4& accA, float4& accB) {
    int k = 0;
    for (; k + 3 < cnt; k += 4) {
        int i0 = sorted[s0 + k];
        int i1 = sorted[s0 + k + 1];
        int i2 = sorted[s0 + k + 2];
        int i3 = sorted[s0 + k + 3];
        float4 v0 = x4[i0 * 8 + q];
        float4 v1 = x4[i1 * 8 + q];
        float4 v2 = x4[i2 * 8 + q];
        float4 v3 = x4[i3 * 8 + q];
        f4add(accA, v0); f4add(accB, v1); f4add(accA, v2); f4add(accB, v3);
    }
    for (; k < cnt; ++k) f4add(accA, x4[sorted[s0 + k] * 8 + q]);
}

// One 512-thread block per 128-node bucket: in-LDS counting sort of the
// bucket's edges by local dst, then atomic-free register accumulation.
__global__ void __launch_bounds__(512)
sort_aggregate_kernel(const float4* __restrict__ x4,
                      const int* __restrict__ goff,
                      const int* __restrict__ packed,
                      float4* __restrict__ out4,
                      int n_nodes, int n_edges, int nbuckets) {
    __shared__ int shist[NPB];
    __shared__ int soff[NPB];
    __shared__ int scur[NPB];
    __shared__ int sorted[CAP];

    int b = blockIdx.x;
    int n0 = b << NPB_SHIFT;
    int t = threadIdx.x;
    int seg_start = goff[b];
    int seg_end   = (b + 1 < nbuckets) ? goff[b + 1] : n_edges;

    int node = t >> 3;        // 0..63 (batch 0: node, batch 1: node+64)
    int q    = t & 7;         // feature quad
    float4 a0A = {0,0,0,0}, a0B = {0,0,0,0};
    float4 a1A = {0,0,0,0}, a1B = {0,0,0,0};
    int deg0 = 0, deg1 = 0;

    for (int pos = seg_start; pos < seg_end; pos += CAP) {
        int chunk = min(CAP, seg_end - pos);
        for (int i = t; i < NPB; i += 512) shist[i] = 0;
        __syncthreads();
        for (int i = t; i < chunk; i += 512)
            atomicAdd(&shist[packed[pos + i] & NPB_MASK], 1);
        __syncthreads();
        if (t < NPB) soff[t] = shist[t];
        __syncthreads();
        for (int off = 1; off < NPB; off <<= 1) {
            int v = (t < NPB && t >= off) ? soff[t - off] : 0;
            __syncthreads();
            if (t < NPB) soff[t] += v;
            __syncthreads();
        }
        if (t < NPB) {
            int e = soff[t] - shist[t];
            soff[t] = e;
            scur[t] = e;
        }
        __syncthreads();
        for (int i = t; i < chunk; i += 512) {
            int p = packed[pos + i];
            int r = atomicAdd(&scur[p & NPB_MASK], 1);
            sorted[r] = p >> NPB_SHIFT;
        }
        __syncthreads();
        {
            int c0 = shist[node];
            accum_node(x4, sorted, soff[node], c0, q, a0A, a0B);
            deg0 += c0;
            int c1 = shist[node + 64];
            accum_node(x4, sorted, soff[node + 64], c1, q, a1A, a1B);
            deg1 += c1;
        }
        __syncthreads();
    }

    int g0 = n0 + node;
    if (g0 < n_nodes) {
        float inv = 1.0f / (float)max(deg0, 1);
        float4 r;
        r.x = (a0A.x + a0B.x) * inv; r.y = (a0A.y + a0B.y) * inv;
        r.z = (a0A.z + a0B.z) * inv; r.w = (a0A.w + a0B.w) * inv;
        out4[g0 * 8 + q] = r;
    }
    int g1 = n0 + 64 + node;
    if (g1 < n_nodes) {
        float inv = 1.0f / (float)max(deg1, 1);
        float4 r;
        r.x = (a1A.x + a1B.x) * inv; r.y = (a1A.y + a1B.y) * inv;
        r.z = (a1A.z + a1B.z) * inv; r.w = (a1A.w + a1B.w) * inv;
        out4[g1 * 8 + q] = r;
    }
}

// ================= fallback: sorted (pull) path =================

__global__ void hist_kernel(const int* __restrict__ dst, int* __restrict__ counts,
                            int n_edges) {
    int t = blockIdx.x * blockDim.x + threadIdx.x;
    if (t < n_edges) atomicAdd(&counts[dst[t]], 1);
}

__global__ void scan_part1(const int* __restrict__ counts,
                           int* __restrict__ block_sums, int n) {
    __shared__ int sh[256];
    int base = blockIdx.x * TILE + threadIdx.x * 32;
    int s = 0;
#pragma unroll
    for (int i = 0; i < 32; ++i) {
        int idx = base + i;
        if (idx < n) s += counts[idx];
    }
    sh[threadIdx.x] = s;
    __syncthreads();
    for (int off = 128; off > 0; off >>= 1) {
        if (threadIdx.x < off) sh[threadIdx.x] += sh[threadIdx.x + off];
        __syncthreads();
    }
    if (threadIdx.x == 0) block_sums[blockIdx.x] = sh[0];
}

__global__ void scan_part2(int* __restrict__ block_sums, int nb) {
    if (blockIdx.x == 0 && threadIdx.x == 0) {
        int run = 0;
        for (int i = 0; i < nb; ++i) {
            int v = block_sums[i];
            block_sums[i] = run;
            run += v;
        }
    }
}

__global__ void scan_part3(const int* __restrict__ counts,
                           const int* __restrict__ block_sums,
                           int* __restrict__ offsets, int n) {
    __shared__ int sh[256];
    int tid = threadIdx.x;
    int base = blockIdx.x * TILE + tid * 32;
    int local[32];
    int s = 0;
#pragma unroll
    for (int i = 0; i < 32; ++i) {
        int idx = base + i;
        int v = (idx < n) ? counts[idx] : 0;
        local[i] = v;
        s += v;
    }
    sh[tid] = s;
    __syncthreads();
    for (int off = 1; off < 256; off <<= 1) {
        int v = (tid >= off) ? sh[tid - off] : 0;
        __syncthreads();
        sh[tid] += v;
        __syncthreads();
    }
    int run = block_sums[blockIdx.x] + ((tid == 0) ? 0 : sh[tid - 1]);
#pragma unroll
    for (int i = 0; i < 32; ++i) {
        int idx = base + i;
        if (idx < n) offsets[idx] = run;
        run += local[i];
    }
}

__global__ void scatter_sort_kernel(const int* __restrict__ src,
                                    const int* __restrict__ dst,
                                    int* __restrict__ cursors,
                                    int* __restrict__ sorted_src,
                                    int n_edges) {
    int t = blockIdx.x * blockDim.x + threadIdx.x;
    if (t < n_edges) {
        int pos = atomicAdd(&cursors[dst[t]], 1);
        sorted_src[pos] = src[t];
    }
}

__global__ void aggregate_kernel(const float* __restrict__ x,
                                 const int* __restrict__ seg_end,
                                 const int* __restrict__ sorted_src,
                                 float4* __restrict__ out,
                                 int n_nodes) {
    int t = blockIdx.x * blockDim.x + threadIdx.x;
    int n = t >> 3;
    if (n >= n_nodes) return;
    int q = t & 7;
    int end   = seg_end[n];
    int start = (n == 0) ? 0 : seg_end[n - 1];
    const float4* x4 = (const float4*)x;
    float4 acc0 = make_float4(0.f, 0.f, 0.f, 0.f);
    float4 acc1 = make_float4(0.f, 0.f, 0.f, 0.f);
    int k = start;
    for (; k + 1 < end; k += 2) {
        int s0 = sorted_src[k];
        int s1 = sorted_src[k + 1];
        f4add(acc0, x4[s0 * 8 + q]);
        f4add(acc1, x4[s1 * 8 + q]);
    }
    if (k < end) f4add(acc0, x4[sorted_src[k] * 8 + q]);
    float inv = 1.0f / (float)max(end - start, 1);
    float4 r;
    r.x = (acc0.x + acc1.x) * inv;
    r.y = (acc0.y + acc1.y) * inv;
    r.z = (acc0.z + acc1.z) * inv;
    r.w = (acc0.w + acc1.w) * inv;
    out[n * 8 + q] = r;
}

// ================= launch =================

extern "C" void kernel_launch(void* const* d_in, const int* in_sizes, int n_in,
                              void* d_out, int out_size, void* d_ws, size_t ws_size,
                              hipStream_t stream) {
    const float* x   = (const float*)d_in[0];
    const int*   src = (const int*)d_in[1];
    const int*   dst = (const int*)d_in[2];
    float* out = (float*)d_out;

    int n_nodes = in_sizes[0] / DIM;
    int n_edges = in_sizes[1];
    int n_out   = out_size;

    int nbuckets = (n_nodes + NPB - 1) >> NPB_SHIFT;
    int nblocks  = (n_edges + PCHUNK - 1) / PCHUNK;
    size_t need_new = ((size_t)nblocks * nbuckets + 2 * nbuckets + n_edges)
                      * sizeof(int);
    bool pack_ok = (n_nodes < (1 << 24)) && (nbuckets <= MAXB) &&
                   (nblocks <= MAXBLK);

    if (pack_ok && ws_size >= need_new) {
        int* H      = (int*)d_ws;                       // [nblocks][nbuckets]
        int* colsum = H + (size_t)nblocks * nbuckets;   // [nbuckets]
        int* goff   = colsum + nbuckets;                // [nbuckets] (preserved)
        int* packed = goff + nbuckets;                  // [n_edges]

        hist_kernel_na<<<nblocks, 512, 0, stream>>>(dst, H, n_edges, nbuckets);
        colscan_kernel<<<nbuckets, MAXBLK, 0, stream>>>(H, colsum, nblocks,
                                                        nbuckets);
        exscan_kernel<<<1, MAXB, 0, stream>>>(colsum, goff, nbuckets);
        partition_kernel_na<<<nblocks, 512, 0, stream>>>(src, dst, H, goff,
                                                         packed, n_edges,
                                                         nbuckets);
        sort_aggregate_kernel<<<nbuckets, 512, 0, stream>>>((const float4*)x, goff,
                                                            packed, (float4*)out,
                                                            n_nodes, n_edges,
                                                            nbuckets);
    } else {
        // fallback: dst-sorted pull path (round-4 pipeline)
        int nb = (n_nodes + TILE - 1) / TILE;
        int* counts     = (int*)d_ws;
        int* offsets    = counts + n_nodes;
        int* sorted_src = offsets + n_nodes;
        int* block_sums = sorted_src + n_edges;

        zero_i32_kernel<<<(n_nodes + 255) / 256, 256, 0, stream>>>(counts, n_nodes);
        int eb = (n_edges + 255) / 256;
        hist_kernel<<<eb, 256, 0, stream>>>(dst, counts, n_edges);
        scan_part1<<<nb, 256, 0, stream>>>(counts, block_sums, n_nodes);
        scan_part2<<<1, 64, 0, stream>>>(block_sums, nb);
        scan_part3<<<nb, 256, 0, stream>>>(counts, block_sums, offsets, n_nodes);
        scatter_sort_kernel<<<eb, 256, 0, stream>>>(src, dst, offsets, sorted_src,
                                                    n_edges);
        int athreads = n_nodes * 8;
        int ab = (athreads + 255) / 256;
        aggregate_kernel<<<ab, 256, 0, stream>>>(x, offsets, sorted_src,
                                                 (float4*)out, n_nodes);
    }
}